// Round 5
// baseline (639.618 us; speedup 1.0000x reference)
//
#include <hip/hip_runtime.h>

// B=131072, T=16, D=2, H=64. 16 rows/wave, now 8 waves/block (128 rows).
// R10 (from R9 post-mortem): R9's op-count cuts were ~neutral -> trans ops are
// cheap (~full-rate); 30% VALU-idle = latency stalls in the serial step chain.
// Lever: occupancy. Weight tables (whhtab+w1tab+gi_tab = 23.5KB) were duplicated
// per 4-wave block; amortize over 8-wave/128-row blocks:
//   LDS = 23552 + 18432(hbuf) + 10240(hidbuf) + 1024(ystate) = 53248 B
//   -> 3 blocks/CU x 8 waves = 24 waves/CU (vs 16). +50% latency hiding.
// launch_bounds(512,6): cap 85 VGPR (R9 measured exactly 84 with same hot loop).
// Math identical to R9 (proven: fused single-rcp tail, deferred log).
#define BSZ 131072
#define TT  16
#define RPB 128
#define BLK 512

#define LOG2E      1.4426950408889634f
#define NEG_LOG2E  (-1.4426950408889634f)
#define TWO_LOG2E  2.8853900817779268f

typedef __bf16 bf16x8 __attribute__((ext_vector_type(8)));
typedef float  f32x4  __attribute__((ext_vector_type(4)));

#define MFMA(a,b,c) __builtin_amdgcn_mfma_f32_16x16x32_bf16((a),(b),(c),0,0,0)

static __device__ __forceinline__ float rcp_f(float v){ float r; asm("v_rcp_f32 %0, %1" : "=v"(r) : "v"(v)); return r; }
static __device__ __forceinline__ float exp2_f(float v){ float r; asm("v_exp_f32 %0, %1" : "=v"(r) : "v"(v)); return r; }

__global__ __launch_bounds__(BLK, 6) void flow10(
    const float* __restrict__ x,     // (B,16,2)
    const float* __restrict__ z,     // (B,64)
    const float* __restrict__ W_ih,  // (192,2)
    const float* __restrict__ W_hh,  // (192,64)
    const float* __restrict__ b_ih,  // (192)
    const float* __restrict__ b_hh,  // (192)
    const float* __restrict__ W1,    // (64,32)
    const float* __restrict__ b1,    // (32)
    const float* __restrict__ W2,    // (32,4)
    const float* __restrict__ b2,    // (4)
    float* __restrict__ y_out,       // (B,16,2)
    float* __restrict__ lad_out)     // (B)
{
  // LDS: 16384 + 4096 + 3072 + 18432 + 10240 + 1024 = 53248 B (3 blocks/CU)
  __shared__ __align__(16) __bf16 whhtab[16*64*8];  // z/n-gate B-frags [f][lane][8] (pre-scaled)
  __shared__ __align__(16) __bf16 w1tab[4*64*8];    // W1 B-frags
  __shared__ __align__(16) float4 gi_tab[192];      // {Wih0, Wih1, bias, 0} (pre-scaled)
  __shared__ __align__(16) __bf16 hbuf[RPB*72];     // h bf16, stride 72; cols 64..71 pad
  __shared__ __align__(16) __bf16 hidbuf[RPB*40];   // hidden, stride 40; cols 32..39 = ls pad
  __shared__ __align__(16) float  ystate[RPB*2];    // y_{t-1} [row][comp]

  const int tid  = threadIdx.x;
  const int lane = tid & 63, wave = tid >> 6;
  const int quad = lane >> 4, n16 = lane & 15;
  const int gb   = blockIdx.x * RPB;
  const f32x4 zero = {0.f,0.f,0.f,0.f};

  // ---------- one-time staging (512 threads) ----------
  if (tid < 192) {  // gi_tab, pre-scaled
    const int j = tid;
    const float sc = (j < 128) ? NEG_LOG2E : TWO_LOG2E;
    const float w0 = W_ih[2*j]*sc, w1 = W_ih[2*j+1]*sc;
    const float bi = b_ih[j], bh = b_hh[j];
    gi_tab[j] = make_float4(w0, w1, ((j < 128) ? bi + bh : bi)*sc, 0.f);
  }
  // whhtab: f = (gate-1)*8 + g*2 + kt, gate 1=z (x -log2e), 2=n (x 2log2e)
  #pragma unroll
  for (int i = 0; i < 2; ++i) {
    const int f = i*8 + wave;
    const int gate = 1 + (f >> 3), g = (f >> 1) & 3, kt = f & 1;
    const float sc = (gate == 1) ? NEG_LOG2E : TWO_LOG2E;
    const float* p = W_hh + (size_t)((gate*4 + g)*16 + n16)*64 + kt*32 + quad*8;
    bf16x8 v;
    #pragma unroll
    for (int j = 0; j < 8; ++j) v[j] = (__bf16)(p[j]*sc);
    *(bf16x8*)&whhtab[(f*64 + lane)*8] = v;
  }
  if (wave < 4) { // w1tab: frag f = c2*2+kt, one per wave (unscaled)
    const int f = wave, c2 = f >> 1, kt = f & 1;
    bf16x8 v;
    #pragma unroll
    for (int j = 0; j < 8; ++j)
      v[j] = (__bf16)W1[(size_t)(kt*32 + quad*8 + j)*32 + c2*16 + n16];
    *(bf16x8*)&w1tab[(f*64 + lane)*8] = v;
  }
  if (tid < 256) ystate[tid] = 0.f;
  #pragma unroll
  for (int r4 = 0; r4 < 4; ++r4) {  // z -> hbuf (bf16), 128 rows
    const int row = (tid >> 4) + r4*32, col = (tid & 15)*4;
    const float4 zv = *(const float4*)&z[(size_t)(gb + row)*64 + col];
    hbuf[row*72 + col+0] = (__bf16)zv.x; hbuf[row*72 + col+1] = (__bf16)zv.y;
    hbuf[row*72 + col+2] = (__bf16)zv.z; hbuf[row*72 + col+3] = (__bf16)zv.w;
  }

  // r-gate B-frags in regs (pre-scaled by -log2e): 8 x bf16x8 = 32 VGPR
  bf16x8 Whr[4][2];
  #pragma unroll
  for (int g = 0; g < 4; ++g)
    #pragma unroll
    for (int kt = 0; kt < 2; ++kt) {
      const float* p = W_hh + (size_t)(g*16 + n16)*64 + kt*32 + quad*8;
      bf16x8 v;
      #pragma unroll
      for (int j = 0; j < 8; ++j) v[j] = (__bf16)(p[j]*NEG_LOG2E);
      Whr[g][kt] = v;
    }
  // W2 B-frag in regs (4 VGPR)
  bf16x8 W2f;
  #pragma unroll
  for (int j = 0; j < 8; ++j)
    W2f[j] = (n16 < 4) ? (__bf16)W2[(size_t)(quad*8 + j)*4 + n16] : (__bf16)0.f;

  // h state fp32 C-layout: hst[g][i] = h[quad*4+i][g*16+n16]
  f32x4 hst[4];
  #pragma unroll
  for (int g = 0; g < 4; ++g)
    #pragma unroll
    for (int i = 0; i < 4; ++i)
      hst[g][i] = z[(size_t)(gb + wave*16 + quad*4 + i)*64 + g*16 + n16];
  float bhn[4];   // b_hh n-part, scaled (folded into cn C-init)
  #pragma unroll
  for (int g = 0; g < 4; ++g) bhn[g] = b_hh[128 + g*16 + n16]*TWO_LOG2E;
  const float b1v0 = b1[n16], b1v1 = b1[16 + n16];
  const float b2ln = (n16 < 4) ? b2[n16] : 0.f;

  __syncthreads();  // only barrier

  const int arow = wave*16 + n16;
  bf16x8 a0 = *(const bf16x8*)&hbuf[arow*72 + quad*8];
  bf16x8 a1 = *(const bf16x8*)&hbuf[arow*72 + 32 + quad*8];

  // epilogue: 32 lanes, comp = lane>>4, row = lane&15
  const int erow = wave*16 + (lane & 15);
  const int comp = (lane >> 4) & 1;
  const float* xp = x + (size_t)(gb + erow)*(TT*2) + comp;
  float*       yp = y_out + (size_t)(gb + erow)*(TT*2) + comp;
  float yc = 0.f, prodS = 1.0f;

  #pragma unroll 1
  for (int t = 0; t < TT; ++t) {
    const float xt = (lane < 32) ? xp[t*2] : 0.f;   // issue global load early
    float ys0[4], ys1[4];
    #pragma unroll
    for (int i = 0; i < 4; ++i) {
      const float2 yv = *(const float2*)&ystate[(wave*16 + quad*4 + i)*2];
      ys0[i] = yv.x; ys1[i] = yv.y;
    }

    // ---- GRU per col-group g (all pre-activations in scaled domain) ----
    #pragma unroll
    for (int g = 0; g < 4; ++g) {
      const bf16x8 bz0 = *(const bf16x8*)&whhtab[((g*2    )*64 + lane)*8];
      const bf16x8 bz1 = *(const bf16x8*)&whhtab[((g*2 + 1)*64 + lane)*8];
      const bf16x8 bn0 = *(const bf16x8*)&whhtab[((8 + g*2    )*64 + lane)*8];
      const bf16x8 bn1 = *(const bf16x8*)&whhtab[((8 + g*2 + 1)*64 + lane)*8];
      f32x4 cr = MFMA(a0, Whr[g][0], zero); cr = MFMA(a1, Whr[g][1], cr);
      f32x4 cz = MFMA(a0, bz0, zero);       cz = MFMA(a1, bz1, cz);
      const f32x4 cninit = {bhn[g], bhn[g], bhn[g], bhn[g]};
      f32x4 cn = MFMA(a0, bn0, cninit);     cn = MFMA(a1, bn1, cn);
      const float4 Tr = gi_tab[      g*16 + n16];
      const float4 Tz = gi_tab[ 64 + g*16 + n16];
      const float4 Tn = gi_tab[128 + g*16 + n16];
      #pragma unroll
      for (int i = 0; i < 4; ++i) {
        const float sr  = fmaf(Tr.x, ys0[i], fmaf(Tr.y, ys1[i], Tr.z)) + cr[i]; // = -log2e*vr
        const float sz  = fminf(fmaf(Tz.x, ys0[i], fmaf(Tz.y, ys1[i], Tz.z)) + cz[i], 61.f);
        const float gin = fmaf(Tn.x, ys0[i], fmaf(Tn.y, ys1[i], Tn.z));         // = 2log2e*(..)
        const float r   = rcp_f(1.0f + exp2_f(sr));                             // sigmoid(vr)
        const float pre = fminf(fmaf(r, cn[i], gin), 61.f);                     // = 2log2e*vn
        // fused tail: u = 1/(1+Ez), tanh = (S-2)/S; hv = u*h + (1-u)*tanh
        //           = [h*S + Ez*(S-2)] / [S*(Ez+1)]
        const float Ez  = exp2_f(sz);
        const float En  = exp2_f(pre);
        const float S   = En + 1.0f;
        const float num = fmaf(S, hst[g][i] + Ez, Ez * -2.0f);
        const float den = fmaf(S, Ez, S);
        const float hv  = num * rcp_f(den);
        hst[g][i] = hv;
        hbuf[(wave*16 + quad*4 + i)*72 + g*16 + n16] = (__bf16)hv;
      }
    }

    a0 = *(const bf16x8*)&hbuf[arow*72 + quad*8];
    a1 = *(const bf16x8*)&hbuf[arow*72 + 32 + quad*8];

    // ---- MLP1 ----
    #pragma unroll
    for (int c2 = 0; c2 < 2; ++c2) {
      const float bb = c2 ? b1v1 : b1v0;
      const f32x4 binit = {bb, bb, bb, bb};
      f32x4 hc = MFMA(a0, *(const bf16x8*)&w1tab[((c2*2  )*64 + lane)*8], binit);
      hc       = MFMA(a1, *(const bf16x8*)&w1tab[((c2*2+1)*64 + lane)*8], hc);
      #pragma unroll
      for (int i = 0; i < 4; ++i)
        hidbuf[(wave*16 + quad*4 + i)*40 + c2*16 + n16] = (__bf16)fmaxf(hc[i], 0.f);
    }

    // ---- MLP2: ls -> hidbuf pad (cols 32..39 as 4 floats) ----
    {
      const bf16x8 ha = *(const bf16x8*)&hidbuf[arow*40 + quad*8];
      const f32x4 b2init = {b2ln, b2ln, b2ln, b2ln};
      const f32x4 ls = MFMA(ha, W2f, b2init);
      if (n16 < 4) {
        #pragma unroll
        for (int i = 0; i < 4; ++i)
          ((float*)&hidbuf[(wave*16 + quad*4 + i)*40 + 32])[n16] = ls[i];
      }
    }

    // ---- epilogue (32 lanes): y update + scale product (log deferred) ----
    if (lane < 32) {
      const float* lsp = (const float*)&hidbuf[erow*40 + 32];
      const float lc = lsp[comp];
      const float l2 = lsp[2 + comp];
      const float s  = __logf(1.0f + __expf(l2)) + 0.001f;
      yc += lc + s * xt;
      prodS *= s;
      ystate[erow*2 + comp] = yc;
      yp[t*2] = yc;
    }
  }

  // logabsdet = log(prod_t s_t) per comp, summed over comps (matches reference)
  const float ll  = __logf(prodS);
  const float llo = __shfl(ll, lane ^ 16, 64);
  if (lane < 16) lad_out[gb + wave*16 + lane] = ll + llo;
}

extern "C" void kernel_launch(void* const* d_in, const int* in_sizes, int n_in,
                              void* d_out, int out_size, void* d_ws, size_t ws_size,
                              hipStream_t stream) {
  const float* x    = (const float*)d_in[0];
  const float* z    = (const float*)d_in[1];
  const float* W_ih = (const float*)d_in[2];
  const float* W_hh = (const float*)d_in[3];
  const float* b_ih = (const float*)d_in[4];
  const float* b_hh = (const float*)d_in[5];
  const float* W1   = (const float*)d_in[6];
  const float* b1   = (const float*)d_in[7];
  const float* W2   = (const float*)d_in[8];
  const float* b2   = (const float*)d_in[9];

  float* y_out   = (float*)d_out;
  float* lad_out = y_out + (size_t)BSZ * TT * 2;

  dim3 grid(BSZ / RPB), block(BLK);
  hipLaunchKernelGGL(flow10, grid, block, 0, stream,
                     x, z, W_ih, W_hh, b_ih, b_hh, W1, b1, W2, b2,
                     y_out, lad_out);
}

// Round 6
// 520.493 us; speedup vs baseline: 1.2289x; 1.2289x over previous
//
#include <hip/hip_runtime.h>

// B=131072, T=16, D=2, H=64. 16 rows/wave, 8 waves/block (128 rows).
// R11 (from R10 post-mortem): R10's occupancy plan was right but died on VGPR:
// cap 85 (512/6) vs ~85+ live -> catastrophic spill (FETCH 1.6GB). Fix = same
// structure, live set shaved 11 regs so alloc <=80 fits cap 85 with margin:
//   - bhn[4] -> gi_tab.w (free: rides the existing Tn float4 read)      -4
//   - W2f -> W2tab in LDS (1KB, +1 ds_read_b128/step)                   -4
//   - b1v0/b1v1/b2ln -> b1tab float4 in LDS (256B, +1 ds_read/step)     -3
// LDS: 16384+4096+3072+18432+10240+1024+1024+256 = 54528 B; x3 = 163584
// <= 163840 -> 3 blocks/CU x 8 waves = 24 waves/CU (vs R9's 16).
// Hot-loop math identical to R9 (proven: fused single-rcp tail, deferred log).
#define BSZ 131072
#define TT  16
#define RPB 128
#define BLK 512

#define NEG_LOG2E  (-1.4426950408889634f)
#define TWO_LOG2E  2.8853900817779268f

typedef __bf16 bf16x8 __attribute__((ext_vector_type(8)));
typedef float  f32x4  __attribute__((ext_vector_type(4)));

#define MFMA(a,b,c) __builtin_amdgcn_mfma_f32_16x16x32_bf16((a),(b),(c),0,0,0)

static __device__ __forceinline__ float rcp_f(float v){ float r; asm("v_rcp_f32 %0, %1" : "=v"(r) : "v"(v)); return r; }
static __device__ __forceinline__ float exp2_f(float v){ float r; asm("v_exp_f32 %0, %1" : "=v"(r) : "v"(v)); return r; }

__global__ __launch_bounds__(BLK, 6) void flow11(
    const float* __restrict__ x,     // (B,16,2)
    const float* __restrict__ z,     // (B,64)
    const float* __restrict__ W_ih,  // (192,2)
    const float* __restrict__ W_hh,  // (192,64)
    const float* __restrict__ b_ih,  // (192)
    const float* __restrict__ b_hh,  // (192)
    const float* __restrict__ W1,    // (64,32)
    const float* __restrict__ b1,    // (32)
    const float* __restrict__ W2,    // (32,4)
    const float* __restrict__ b2,    // (4)
    float* __restrict__ y_out,       // (B,16,2)
    float* __restrict__ lad_out)     // (B)
{
  __shared__ __align__(16) __bf16 whhtab[16*64*8];  // z/n-gate B-frags (pre-scaled)
  __shared__ __align__(16) __bf16 w1tab[4*64*8];    // W1 B-frags
  __shared__ __align__(16) __bf16 W2tab[64*8];      // W2 B-frag per lane
  __shared__ __align__(16) float4 gi_tab[192];      // {Wih0, Wih1, bias, bhn} (pre-scaled)
  __shared__ __align__(16) float4 b1tab[16];        // {b1[n16], b1[16+n16], b2ln, 0}
  __shared__ __align__(16) __bf16 hbuf[RPB*72];     // h bf16, stride 72; cols 64..71 pad
  __shared__ __align__(16) __bf16 hidbuf[RPB*40];   // hidden, stride 40; cols 32..39 = ls pad
  __shared__ __align__(16) float  ystate[RPB*2];    // y_{t-1} [row][comp]

  const int tid  = threadIdx.x;
  const int lane = tid & 63, wave = tid >> 6;
  const int quad = lane >> 4, n16 = lane & 15;
  const int gb   = blockIdx.x * RPB;
  const f32x4 zero = {0.f,0.f,0.f,0.f};

  // ---------- one-time staging (512 threads) ----------
  if (tid < 192) {  // gi_tab, pre-scaled; .w = scaled b_hh n-part (cn C-init)
    const int j = tid;
    const float sc = (j < 128) ? NEG_LOG2E : TWO_LOG2E;
    const float w0 = W_ih[2*j]*sc, w1 = W_ih[2*j+1]*sc;
    const float bi = b_ih[j], bh = b_hh[j];
    const float bias = ((j < 128) ? bi + bh : bi)*sc;
    const float wslot = (j < 128) ? 0.f : bh*TWO_LOG2E;
    gi_tab[j] = make_float4(w0, w1, bias, wslot);
  }
  if (tid < 16) {   // b1tab: {b1 lo, b1 hi, b2ln, 0}
    b1tab[tid] = make_float4(b1[tid], b1[16 + tid], (tid < 4) ? b2[tid] : 0.f, 0.f);
  }
  if (tid < 64) {   // W2tab: per-lane MLP2 B-frag
    const int q = tid >> 4, c = tid & 15;
    bf16x8 v;
    #pragma unroll
    for (int j = 0; j < 8; ++j)
      v[j] = (c < 4) ? (__bf16)W2[(size_t)(q*8 + j)*4 + c] : (__bf16)0.f;
    *(bf16x8*)&W2tab[tid*8] = v;
  }
  // whhtab: f = (gate-1)*8 + g*2 + kt, gate 1=z (x -log2e), 2=n (x 2log2e)
  #pragma unroll
  for (int i = 0; i < 2; ++i) {
    const int f = i*8 + wave;
    const int gate = 1 + (f >> 3), g = (f >> 1) & 3, kt = f & 1;
    const float sc = (gate == 1) ? NEG_LOG2E : TWO_LOG2E;
    const float* p = W_hh + (size_t)((gate*4 + g)*16 + n16)*64 + kt*32 + quad*8;
    bf16x8 v;
    #pragma unroll
    for (int j = 0; j < 8; ++j) v[j] = (__bf16)(p[j]*sc);
    *(bf16x8*)&whhtab[(f*64 + lane)*8] = v;
  }
  if (wave < 4) { // w1tab: frag f = c2*2+kt
    const int f = wave, c2 = f >> 1, kt = f & 1;
    bf16x8 v;
    #pragma unroll
    for (int j = 0; j < 8; ++j)
      v[j] = (__bf16)W1[(size_t)(kt*32 + quad*8 + j)*32 + c2*16 + n16];
    *(bf16x8*)&w1tab[(f*64 + lane)*8] = v;
  }
  if (tid < 256) ystate[tid] = 0.f;
  #pragma unroll
  for (int r4 = 0; r4 < 4; ++r4) {  // z -> hbuf (bf16), 128 rows
    const int row = (tid >> 4) + r4*32, col = (tid & 15)*4;
    const float4 zv = *(const float4*)&z[(size_t)(gb + row)*64 + col];
    hbuf[row*72 + col+0] = (__bf16)zv.x; hbuf[row*72 + col+1] = (__bf16)zv.y;
    hbuf[row*72 + col+2] = (__bf16)zv.z; hbuf[row*72 + col+3] = (__bf16)zv.w;
  }

  // r-gate B-frags in regs (pre-scaled by -log2e): 8 x bf16x8 = 32 VGPR
  bf16x8 Whr[4][2];
  #pragma unroll
  for (int g = 0; g < 4; ++g)
    #pragma unroll
    for (int kt = 0; kt < 2; ++kt) {
      const float* p = W_hh + (size_t)(g*16 + n16)*64 + kt*32 + quad*8;
      bf16x8 v;
      #pragma unroll
      for (int j = 0; j < 8; ++j) v[j] = (__bf16)(p[j]*NEG_LOG2E);
      Whr[g][kt] = v;
    }

  // h state fp32 C-layout: hst[g][i] = h[quad*4+i][g*16+n16]
  f32x4 hst[4];
  #pragma unroll
  for (int g = 0; g < 4; ++g)
    #pragma unroll
    for (int i = 0; i < 4; ++i)
      hst[g][i] = z[(size_t)(gb + wave*16 + quad*4 + i)*64 + g*16 + n16];

  __syncthreads();  // only barrier

  const int arow = wave*16 + n16;
  bf16x8 a0 = *(const bf16x8*)&hbuf[arow*72 + quad*8];
  bf16x8 a1 = *(const bf16x8*)&hbuf[arow*72 + 32 + quad*8];

  // epilogue: 32 lanes, comp = lane>>4, row = lane&15
  const int erow = wave*16 + (lane & 15);
  const int comp = (lane >> 4) & 1;
  const float* xp = x + (size_t)(gb + erow)*(TT*2) + comp;
  float*       yp = y_out + (size_t)(gb + erow)*(TT*2) + comp;
  float yc = 0.f, prodS = 1.0f;

  #pragma unroll 1
  for (int t = 0; t < TT; ++t) {
    const float xt = (lane < 32) ? xp[t*2] : 0.f;   // issue global load early
    float ys0[4], ys1[4];
    #pragma unroll
    for (int i = 0; i < 4; ++i) {
      const float2 yv = *(const float2*)&ystate[(wave*16 + quad*4 + i)*2];
      ys0[i] = yv.x; ys1[i] = yv.y;
    }

    // ---- GRU per col-group g (all pre-activations in scaled domain) ----
    #pragma unroll
    for (int g = 0; g < 4; ++g) {
      const bf16x8 bz0 = *(const bf16x8*)&whhtab[((g*2    )*64 + lane)*8];
      const bf16x8 bz1 = *(const bf16x8*)&whhtab[((g*2 + 1)*64 + lane)*8];
      const bf16x8 bn0 = *(const bf16x8*)&whhtab[((8 + g*2    )*64 + lane)*8];
      const bf16x8 bn1 = *(const bf16x8*)&whhtab[((8 + g*2 + 1)*64 + lane)*8];
      const float4 Tr = gi_tab[      g*16 + n16];
      const float4 Tz = gi_tab[ 64 + g*16 + n16];
      const float4 Tn = gi_tab[128 + g*16 + n16];
      f32x4 cr = MFMA(a0, Whr[g][0], zero); cr = MFMA(a1, Whr[g][1], cr);
      f32x4 cz = MFMA(a0, bz0, zero);       cz = MFMA(a1, bz1, cz);
      const f32x4 cninit = {Tn.w, Tn.w, Tn.w, Tn.w};
      f32x4 cn = MFMA(a0, bn0, cninit);     cn = MFMA(a1, bn1, cn);
      #pragma unroll
      for (int i = 0; i < 4; ++i) {
        const float sr  = fmaf(Tr.x, ys0[i], fmaf(Tr.y, ys1[i], Tr.z)) + cr[i]; // = -log2e*vr
        const float sz  = fminf(fmaf(Tz.x, ys0[i], fmaf(Tz.y, ys1[i], Tz.z)) + cz[i], 61.f);
        const float gin = fmaf(Tn.x, ys0[i], fmaf(Tn.y, ys1[i], Tn.z));         // = 2log2e*(..)
        const float r   = rcp_f(1.0f + exp2_f(sr));                             // sigmoid(vr)
        const float pre = fminf(fmaf(r, cn[i], gin), 61.f);                     // = 2log2e*vn
        // fused tail: u = 1/(1+Ez), tanh = (S-2)/S; hv = u*h + (1-u)*tanh
        //           = [h*S + Ez*(S-2)] / [S*(Ez+1)]
        const float Ez  = exp2_f(sz);
        const float En  = exp2_f(pre);
        const float S   = En + 1.0f;
        const float num = fmaf(S, hst[g][i] + Ez, Ez * -2.0f);
        const float den = fmaf(S, Ez, S);
        const float hv  = num * rcp_f(den);
        hst[g][i] = hv;
        hbuf[(wave*16 + quad*4 + i)*72 + g*16 + n16] = (__bf16)hv;
      }
    }

    a0 = *(const bf16x8*)&hbuf[arow*72 + quad*8];
    a1 = *(const bf16x8*)&hbuf[arow*72 + 32 + quad*8];

    const float4 bv = b1tab[n16];   // {b1 lo, b1 hi, b2ln, 0}

    // ---- MLP1 ----
    #pragma unroll
    for (int c2 = 0; c2 < 2; ++c2) {
      const float bb = c2 ? bv.y : bv.x;
      const f32x4 binit = {bb, bb, bb, bb};
      f32x4 hc = MFMA(a0, *(const bf16x8*)&w1tab[((c2*2  )*64 + lane)*8], binit);
      hc       = MFMA(a1, *(const bf16x8*)&w1tab[((c2*2+1)*64 + lane)*8], hc);
      #pragma unroll
      for (int i = 0; i < 4; ++i)
        hidbuf[(wave*16 + quad*4 + i)*40 + c2*16 + n16] = (__bf16)fmaxf(hc[i], 0.f);
    }

    // ---- MLP2: ls -> hidbuf pad (cols 32..39 as 4 floats) ----
    {
      const bf16x8 ha  = *(const bf16x8*)&hidbuf[arow*40 + quad*8];
      const bf16x8 W2f = *(const bf16x8*)&W2tab[lane*8];
      const f32x4 b2init = {bv.z, bv.z, bv.z, bv.z};
      const f32x4 ls = MFMA(ha, W2f, b2init);
      if (n16 < 4) {
        #pragma unroll
        for (int i = 0; i < 4; ++i)
          ((float*)&hidbuf[(wave*16 + quad*4 + i)*40 + 32])[n16] = ls[i];
      }
    }

    // ---- epilogue (32 lanes): y update + scale product (log deferred) ----
    if (lane < 32) {
      const float* lsp = (const float*)&hidbuf[erow*40 + 32];
      const float lc = lsp[comp];
      const float l2 = lsp[2 + comp];
      const float s  = __logf(1.0f + __expf(l2)) + 0.001f;
      yc += lc + s * xt;
      prodS *= s;
      ystate[erow*2 + comp] = yc;
      yp[t*2] = yc;
    }
  }

  // logabsdet = log(prod_t s_t) per comp, summed over comps (matches reference)
  const float ll  = __logf(prodS);
  const float llo = __shfl(ll, lane ^ 16, 64);
  if (lane < 16) lad_out[gb + wave*16 + lane] = ll + llo;
}

extern "C" void kernel_launch(void* const* d_in, const int* in_sizes, int n_in,
                              void* d_out, int out_size, void* d_ws, size_t ws_size,
                              hipStream_t stream) {
  const float* x    = (const float*)d_in[0];
  const float* z    = (const float*)d_in[1];
  const float* W_ih = (const float*)d_in[2];
  const float* W_hh = (const float*)d_in[3];
  const float* b_ih = (const float*)d_in[4];
  const float* b_hh = (const float*)d_in[5];
  const float* W1   = (const float*)d_in[6];
  const float* b1   = (const float*)d_in[7];
  const float* W2   = (const float*)d_in[8];
  const float* b2   = (const float*)d_in[9];

  float* y_out   = (float*)d_out;
  float* lad_out = y_out + (size_t)BSZ * TT * 2;

  dim3 grid(BSZ / RPB), block(BLK);
  hipLaunchKernelGGL(flow11, grid, block, 0, stream,
                     x, z, W_ih, W_hh, b_ih, b_hh, W1, b1, W2, b2,
                     y_out, lad_out);
}

// Round 7
// 253.885 us; speedup vs baseline: 2.5193x; 2.0501x over previous
//
#include <hip/hip_runtime.h>

// B=131072, T=16, D=2, H=64. 16 rows/wave, 8 waves/block (128 rows).
// R12 (from R11 post-mortem): two independent killers found.
//  (1) cap-85 ((512,6)) overrun/allocator-thrash -> massive spill, in BOTH R10
//      and R11, while the IDENTICAL hot loop fit 84 regs at cap 170 (R9).
//  (2) R11's reported LDS was 54784 (+256 vs counted) -> 3 blocks didn't fit.
// R12 = R10 source verbatim (correctness-proven, LDS 53248 reported exact ->
// 3 blocks/CU with 4KB slack) with ONE change: launch_bounds (512,6)->(512,3)
// (cap 170, proven no-spill). If alloc lands at the 256-frame natural of 84:
// 6 waves/SIMD (6x84=504<=512) -> 24 waves/CU. 86-102 -> 20 waves. >102 -> 16
// (R9 status quo). No spill possible; downside bounded.
#define BSZ 131072
#define TT  16
#define RPB 128
#define BLK 512

#define NEG_LOG2E  (-1.4426950408889634f)
#define TWO_LOG2E  2.8853900817779268f

typedef __bf16 bf16x8 __attribute__((ext_vector_type(8)));
typedef float  f32x4  __attribute__((ext_vector_type(4)));

#define MFMA(a,b,c) __builtin_amdgcn_mfma_f32_16x16x32_bf16((a),(b),(c),0,0,0)

static __device__ __forceinline__ float rcp_f(float v){ float r; asm("v_rcp_f32 %0, %1" : "=v"(r) : "v"(v)); return r; }
static __device__ __forceinline__ float exp2_f(float v){ float r; asm("v_exp_f32 %0, %1" : "=v"(r) : "v"(v)); return r; }

__global__ __launch_bounds__(BLK, 3) void flow12(
    const float* __restrict__ x,     // (B,16,2)
    const float* __restrict__ z,     // (B,64)
    const float* __restrict__ W_ih,  // (192,2)
    const float* __restrict__ W_hh,  // (192,64)
    const float* __restrict__ b_ih,  // (192)
    const float* __restrict__ b_hh,  // (192)
    const float* __restrict__ W1,    // (64,32)
    const float* __restrict__ b1,    // (32)
    const float* __restrict__ W2,    // (32,4)
    const float* __restrict__ b2,    // (4)
    float* __restrict__ y_out,       // (B,16,2)
    float* __restrict__ lad_out)     // (B)
{
  // LDS: 16384 + 4096 + 3072 + 18432 + 10240 + 1024 = 53248 B (3 blocks/CU)
  __shared__ __align__(16) __bf16 whhtab[16*64*8];  // z/n-gate B-frags [f][lane][8] (pre-scaled)
  __shared__ __align__(16) __bf16 w1tab[4*64*8];    // W1 B-frags
  __shared__ __align__(16) float4 gi_tab[192];      // {Wih0, Wih1, bias, 0} (pre-scaled)
  __shared__ __align__(16) __bf16 hbuf[RPB*72];     // h bf16, stride 72; cols 64..71 pad
  __shared__ __align__(16) __bf16 hidbuf[RPB*40];   // hidden, stride 40; cols 32..39 = ls pad
  __shared__ __align__(16) float  ystate[RPB*2];    // y_{t-1} [row][comp]

  const int tid  = threadIdx.x;
  const int lane = tid & 63, wave = tid >> 6;
  const int quad = lane >> 4, n16 = lane & 15;
  const int gb   = blockIdx.x * RPB;
  const f32x4 zero = {0.f,0.f,0.f,0.f};

  // ---------- one-time staging (512 threads) ----------
  if (tid < 192) {  // gi_tab, pre-scaled
    const int j = tid;
    const float sc = (j < 128) ? NEG_LOG2E : TWO_LOG2E;
    const float w0 = W_ih[2*j]*sc, w1 = W_ih[2*j+1]*sc;
    const float bi = b_ih[j], bh = b_hh[j];
    gi_tab[j] = make_float4(w0, w1, ((j < 128) ? bi + bh : bi)*sc, 0.f);
  }
  // whhtab: f = (gate-1)*8 + g*2 + kt, gate 1=z (x -log2e), 2=n (x 2log2e)
  #pragma unroll
  for (int i = 0; i < 2; ++i) {
    const int f = i*8 + wave;
    const int gate = 1 + (f >> 3), g = (f >> 1) & 3, kt = f & 1;
    const float sc = (gate == 1) ? NEG_LOG2E : TWO_LOG2E;
    const float* p = W_hh + (size_t)((gate*4 + g)*16 + n16)*64 + kt*32 + quad*8;
    bf16x8 v;
    #pragma unroll
    for (int j = 0; j < 8; ++j) v[j] = (__bf16)(p[j]*sc);
    *(bf16x8*)&whhtab[(f*64 + lane)*8] = v;
  }
  if (wave < 4) { // w1tab: frag f = c2*2+kt
    const int f = wave, c2 = f >> 1, kt = f & 1;
    bf16x8 v;
    #pragma unroll
    for (int j = 0; j < 8; ++j)
      v[j] = (__bf16)W1[(size_t)(kt*32 + quad*8 + j)*32 + c2*16 + n16];
    *(bf16x8*)&w1tab[(f*64 + lane)*8] = v;
  }
  if (tid < 256) ystate[tid] = 0.f;
  #pragma unroll
  for (int r4 = 0; r4 < 4; ++r4) {  // z -> hbuf (bf16), 128 rows
    const int row = (tid >> 4) + r4*32, col = (tid & 15)*4;
    const float4 zv = *(const float4*)&z[(size_t)(gb + row)*64 + col];
    hbuf[row*72 + col+0] = (__bf16)zv.x; hbuf[row*72 + col+1] = (__bf16)zv.y;
    hbuf[row*72 + col+2] = (__bf16)zv.z; hbuf[row*72 + col+3] = (__bf16)zv.w;
  }

  // r-gate B-frags in regs (pre-scaled by -log2e): 8 x bf16x8 = 32 VGPR
  bf16x8 Whr[4][2];
  #pragma unroll
  for (int g = 0; g < 4; ++g)
    #pragma unroll
    for (int kt = 0; kt < 2; ++kt) {
      const float* p = W_hh + (size_t)(g*16 + n16)*64 + kt*32 + quad*8;
      bf16x8 v;
      #pragma unroll
      for (int j = 0; j < 8; ++j) v[j] = (__bf16)(p[j]*NEG_LOG2E);
      Whr[g][kt] = v;
    }
  // W2 B-frag in regs (4 VGPR)
  bf16x8 W2f;
  #pragma unroll
  for (int j = 0; j < 8; ++j)
    W2f[j] = (n16 < 4) ? (__bf16)W2[(size_t)(quad*8 + j)*4 + n16] : (__bf16)0.f;

  // h state fp32 C-layout: hst[g][i] = h[quad*4+i][g*16+n16]
  f32x4 hst[4];
  #pragma unroll
  for (int g = 0; g < 4; ++g)
    #pragma unroll
    for (int i = 0; i < 4; ++i)
      hst[g][i] = z[(size_t)(gb + wave*16 + quad*4 + i)*64 + g*16 + n16];
  float bhn[4];   // b_hh n-part, scaled (folded into cn C-init)
  #pragma unroll
  for (int g = 0; g < 4; ++g) bhn[g] = b_hh[128 + g*16 + n16]*TWO_LOG2E;
  const float b1v0 = b1[n16], b1v1 = b1[16 + n16];
  const float b2ln = (n16 < 4) ? b2[n16] : 0.f;

  __syncthreads();  // only barrier

  const int arow = wave*16 + n16;
  bf16x8 a0 = *(const bf16x8*)&hbuf[arow*72 + quad*8];
  bf16x8 a1 = *(const bf16x8*)&hbuf[arow*72 + 32 + quad*8];

  // epilogue: 32 lanes, comp = lane>>4, row = lane&15
  const int erow = wave*16 + (lane & 15);
  const int comp = (lane >> 4) & 1;
  const float* xp = x + (size_t)(gb + erow)*(TT*2) + comp;
  float*       yp = y_out + (size_t)(gb + erow)*(TT*2) + comp;
  float yc = 0.f, prodS = 1.0f;

  #pragma unroll 1
  for (int t = 0; t < TT; ++t) {
    const float xt = (lane < 32) ? xp[t*2] : 0.f;   // issue global load early
    float ys0[4], ys1[4];
    #pragma unroll
    for (int i = 0; i < 4; ++i) {
      const float2 yv = *(const float2*)&ystate[(wave*16 + quad*4 + i)*2];
      ys0[i] = yv.x; ys1[i] = yv.y;
    }

    // ---- GRU per col-group g (all pre-activations in scaled domain) ----
    #pragma unroll
    for (int g = 0; g < 4; ++g) {
      const bf16x8 bz0 = *(const bf16x8*)&whhtab[((g*2    )*64 + lane)*8];
      const bf16x8 bz1 = *(const bf16x8*)&whhtab[((g*2 + 1)*64 + lane)*8];
      const bf16x8 bn0 = *(const bf16x8*)&whhtab[((8 + g*2    )*64 + lane)*8];
      const bf16x8 bn1 = *(const bf16x8*)&whhtab[((8 + g*2 + 1)*64 + lane)*8];
      f32x4 cr = MFMA(a0, Whr[g][0], zero); cr = MFMA(a1, Whr[g][1], cr);
      f32x4 cz = MFMA(a0, bz0, zero);       cz = MFMA(a1, bz1, cz);
      const f32x4 cninit = {bhn[g], bhn[g], bhn[g], bhn[g]};
      f32x4 cn = MFMA(a0, bn0, cninit);     cn = MFMA(a1, bn1, cn);
      const float4 Tr = gi_tab[      g*16 + n16];
      const float4 Tz = gi_tab[ 64 + g*16 + n16];
      const float4 Tn = gi_tab[128 + g*16 + n16];
      #pragma unroll
      for (int i = 0; i < 4; ++i) {
        const float sr  = fmaf(Tr.x, ys0[i], fmaf(Tr.y, ys1[i], Tr.z)) + cr[i]; // = -log2e*vr
        const float sz  = fminf(fmaf(Tz.x, ys0[i], fmaf(Tz.y, ys1[i], Tz.z)) + cz[i], 61.f);
        const float gin = fmaf(Tn.x, ys0[i], fmaf(Tn.y, ys1[i], Tn.z));         // = 2log2e*(..)
        const float r   = rcp_f(1.0f + exp2_f(sr));                             // sigmoid(vr)
        const float pre = fminf(fmaf(r, cn[i], gin), 61.f);                     // = 2log2e*vn
        // fused tail: u = 1/(1+Ez), tanh = (S-2)/S; hv = u*h + (1-u)*tanh
        //           = [h*S + Ez*(S-2)] / [S*(Ez+1)]
        const float Ez  = exp2_f(sz);
        const float En  = exp2_f(pre);
        const float S   = En + 1.0f;
        const float num = fmaf(S, hst[g][i] + Ez, Ez * -2.0f);
        const float den = fmaf(S, Ez, S);
        const float hv  = num * rcp_f(den);
        hst[g][i] = hv;
        hbuf[(wave*16 + quad*4 + i)*72 + g*16 + n16] = (__bf16)hv;
      }
    }

    a0 = *(const bf16x8*)&hbuf[arow*72 + quad*8];
    a1 = *(const bf16x8*)&hbuf[arow*72 + 32 + quad*8];

    // ---- MLP1 ----
    #pragma unroll
    for (int c2 = 0; c2 < 2; ++c2) {
      const float bb = c2 ? b1v1 : b1v0;
      const f32x4 binit = {bb, bb, bb, bb};
      f32x4 hc = MFMA(a0, *(const bf16x8*)&w1tab[((c2*2  )*64 + lane)*8], binit);
      hc       = MFMA(a1, *(const bf16x8*)&w1tab[((c2*2+1)*64 + lane)*8], hc);
      #pragma unroll
      for (int i = 0; i < 4; ++i)
        hidbuf[(wave*16 + quad*4 + i)*40 + c2*16 + n16] = (__bf16)fmaxf(hc[i], 0.f);
    }

    // ---- MLP2: ls -> hidbuf pad (cols 32..39 as 4 floats) ----
    {
      const bf16x8 ha = *(const bf16x8*)&hidbuf[arow*40 + quad*8];
      const f32x4 b2init = {b2ln, b2ln, b2ln, b2ln};
      const f32x4 ls = MFMA(ha, W2f, b2init);
      if (n16 < 4) {
        #pragma unroll
        for (int i = 0; i < 4; ++i)
          ((float*)&hidbuf[(wave*16 + quad*4 + i)*40 + 32])[n16] = ls[i];
      }
    }

    // ---- epilogue (32 lanes): y update + scale product (log deferred) ----
    if (lane < 32) {
      const float* lsp = (const float*)&hidbuf[erow*40 + 32];
      const float lc = lsp[comp];
      const float l2 = lsp[2 + comp];
      const float s  = __logf(1.0f + __expf(l2)) + 0.001f;
      yc += lc + s * xt;
      prodS *= s;
      ystate[erow*2 + comp] = yc;
      yp[t*2] = yc;
    }
  }

  // logabsdet = log(prod_t s_t) per comp, summed over comps (matches reference)
  const float ll  = __logf(prodS);
  const float llo = __shfl(ll, lane ^ 16, 64);
  if (lane < 16) lad_out[gb + wave*16 + lane] = ll + llo;
}

extern "C" void kernel_launch(void* const* d_in, const int* in_sizes, int n_in,
                              void* d_out, int out_size, void* d_ws, size_t ws_size,
                              hipStream_t stream) {
  const float* x    = (const float*)d_in[0];
  const float* z    = (const float*)d_in[1];
  const float* W_ih = (const float*)d_in[2];
  const float* W_hh = (const float*)d_in[3];
  const float* b_ih = (const float*)d_in[4];
  const float* b_hh = (const float*)d_in[5];
  const float* W1   = (const float*)d_in[6];
  const float* b1   = (const float*)d_in[7];
  const float* W2   = (const float*)d_in[8];
  const float* b2   = (const float*)d_in[9];

  float* y_out   = (float*)d_out;
  float* lad_out = y_out + (size_t)BSZ * TT * 2;

  dim3 grid(BSZ / RPB), block(BLK);
  hipLaunchKernelGGL(flow12, grid, block, 0, stream,
                     x, z, W_ih, W_hh, b_ih, b_hh, W1, b1, W2, b2,
                     y_out, lad_out);
}